// Round 3
// baseline (376.685 us; speedup 1.0000x reference)
//
#include <hip/hip_runtime.h>
#include <math.h>

#define BN 1024
#define SN 64
#define DN 256
#define CHN 1024
#define GRP 16

__device__ __forceinline__ float gelu_exact(float x) {
    return 0.5f * x * (1.0f + erff(x * 0.70710678118654752440f));
}

// K1: scene logits + log_softmax + argmax. One block per sample b, 256 thr = 4 waves.
__global__ __launch_bounds__(256) void k_scene(
    const float* __restrict__ dt, const float* __restrict__ dr,
    const float* __restrict__ Wsc, const float* __restrict__ bsc,
    float* __restrict__ out_logd, int* __restrict__ max_idx)
{
    int b = blockIdx.x;
    int tid = threadIdx.x;
    int lane = tid & 63;
    int wave = tid >> 6;
    __shared__ float part[SN][65];   // +1 pad: reduction read is 2-way (free)
    __shared__ float logits[SN];

    float4 wt = *(const float4*)&Wsc[4 * lane];
    float4 wr = *(const float4*)&Wsc[DN + 4 * lane];
    const float* pt = dt + (size_t)b * SN * DN + 4 * lane;
    const float* pr = dr + (size_t)b * SN * DN + 4 * lane;
    float bias0 = bsc[0];

    float p[16];
    #pragma unroll 8
    for (int k = 0; k < 16; k++) {
        int s = wave * 16 + k;          // each wave streams a contiguous 16KB chunk
        float4 t4 = *(const float4*)&pt[s * DN];
        float4 r4 = *(const float4*)&pr[s * DN];
        p[k] = t4.x * wt.x + t4.y * wt.y + t4.z * wt.z + t4.w * wt.w
             + r4.x * wr.x + r4.y * wr.y + r4.z * wr.z + r4.w * wr.w;
    }
    #pragma unroll
    for (int k = 0; k < 16; k++) part[wave * 16 + k][lane] = p[k];
    __syncthreads();

    {
        int s = tid >> 2, q = tid & 3;
        float sum = 0.f;
        #pragma unroll
        for (int j = 0; j < 16; j++) sum += part[s][q * 16 + j];
        sum += __shfl_xor(sum, 1);
        sum += __shfl_xor(sum, 2);
        if (q == 0) logits[s] = sum + bias0;
    }
    __syncthreads();

    if (wave == 0) {
        float l = logits[lane];
        float m = l; int idx = lane;
        #pragma unroll
        for (int off = 32; off >= 1; off >>= 1) {
            float om = __shfl_xor(m, off);
            int oidx = __shfl_xor(idx, off);
            if (om > m || (om == m && oidx < idx)) { m = om; idx = oidx; }
        }
        float e = expf(l - m);
        float ssum = e;
        #pragma unroll
        for (int off = 32; off >= 1; off >>= 1) ssum += __shfl_xor(ssum, off);
        float logZ = m + logf(ssum);
        out_logd[b * SN + lane] = l - logZ;
        if (lane == 0) max_idx[b] = idx;
    }
}

// K2: fused pose-bias init + scene binning.
__global__ __launch_bounds__(256) void k_prep(
    const int* __restrict__ max_idx,
    const float* __restrict__ bt_o, const float* __restrict__ br_o,
    float* __restrict__ pose, int* __restrict__ counts, int* __restrict__ lists)
{
    int t = blockIdx.x * blockDim.x + threadIdx.x;
    if (t < BN * 7) {
        int b = t / 7, o = t % 7;
        int s = max_idx[b];
        pose[t] = (o < 3) ? bt_o[s * 3 + o] : br_o[s * 4 + (o - 3)];
    }
    if (t < BN) {
        int s = max_idx[t];
        int pos = atomicAdd(&counts[s], 1);
        lists[s * BN + pos] = t;
    }
}

// K3: expert MLP heads. Item space = scene x type x CH-chunk(4) x sample-group,
// enumerated via an in-block prefix scan over counts; block i takes item i.
// Equal-size items (256KB weight stream) -> perfect round-robin balance.
// Double-buffered register prefetch keeps 8 weight loads in flight continuously.
__global__ __launch_bounds__(128) void k_expert(
    const float* __restrict__ dt, const float* __restrict__ dr,
    const float* __restrict__ Wt_h, const float* __restrict__ bt_h, const float* __restrict__ Wt_o,
    const float* __restrict__ Wr_h, const float* __restrict__ br_h, const float* __restrict__ Wr_o,
    const int* __restrict__ counts, const int* __restrict__ lists,
    float* __restrict__ pose)
{
    __shared__ float g[GRP][DN];     // 16 KB gathered descriptors
    __shared__ int pref[SN + 1];
    __shared__ int bl[GRP];
    int tid = threadIdx.x;
    int lane = tid & 63;
    int wave = tid >> 6;

    // group-count prefix scan (wave 0)
    if (wave == 0) {
        int c = counts[lane];
        int ng = (c + 15) >> 4;
        #pragma unroll
        for (int off = 1; off < 64; off <<= 1) {
            int v = __shfl_up(ng, off);
            if (lane >= off) ng += v;
        }
        pref[lane + 1] = ng;
        if (lane == 0) pref[0] = 0;
    }
    __syncthreads();

    int q = blockIdx.x;
    if (q >= pref[SN] * 8) return;   // uniform exit (<=992 items total)

    int s = 0;
    while (pref[s + 1] * 8 <= q) s++;
    int r = q - pref[s] * 8;
    int grp = r >> 3;
    int z = (r >> 2) & 1;
    int c4 = r & 3;

    int cnt = counts[s];
    int base = grp * GRP;
    int n = min(GRP, cnt - base);

    const float* Wh; const float* bh; const float* Wo; const float* descs; int no, ob;
    if (z == 0) {
        Wh = Wt_h + (size_t)s * DN * CHN; bh = bt_h + s * CHN;
        Wo = Wt_o + (size_t)s * CHN * 3;  descs = dt; no = 3; ob = 0;
    } else {
        Wh = Wr_h + (size_t)s * DN * CHN; bh = br_h + s * CHN;
        Wo = Wr_o + (size_t)s * CHN * 4;  descs = dr; no = 4; ob = 3;
    }

    for (int i = 0; i < GRP; i++) {
        int bi = 0; float v0 = 0.f, v1 = 0.f;
        if (i < n) {
            bi = lists[s * BN + base + i];
            const float* src = descs + (size_t)bi * SN * DN + s * DN;
            v0 = src[tid]; v1 = src[tid + 128];
        }
        g[i][tid] = v0; g[i][tid + 128] = v1;
        if (tid == 0) bl[i] = bi;
    }
    __syncthreads();

    int h0 = c4 * 256 + 2 * tid;     // this thread's pair of hidden units
    const float* wp = Wh + h0;
    float2 acc[GRP];
    #pragma unroll
    for (int i = 0; i < GRP; i++) acc[i] = make_float2(0.f, 0.f);

    float2 w0[8], w1[8];
    #pragma unroll
    for (int rr = 0; rr < 8; rr++) w0[rr] = *(const float2*)&wp[(size_t)rr * CHN];

    for (int db = 0; db < DN; db += 16) {
        // prefetch rows db+8..db+15 while computing with rows db..db+7
        #pragma unroll
        for (int rr = 0; rr < 8; rr++) w1[rr] = *(const float2*)&wp[(size_t)(db + 8 + rr) * CHN];
        #pragma unroll
        for (int i = 0; i < GRP; i++) {
            float4 ga = *(const float4*)&g[i][db];
            float4 gb = *(const float4*)&g[i][db + 4];
            acc[i].x += ga.x*w0[0].x + ga.y*w0[1].x + ga.z*w0[2].x + ga.w*w0[3].x
                      + gb.x*w0[4].x + gb.y*w0[5].x + gb.z*w0[6].x + gb.w*w0[7].x;
            acc[i].y += ga.x*w0[0].y + ga.y*w0[1].y + ga.z*w0[2].y + ga.w*w0[3].y
                      + gb.x*w0[4].y + gb.y*w0[5].y + gb.z*w0[6].y + gb.w*w0[7].y;
        }
        if (db + 16 < DN) {
            #pragma unroll
            for (int rr = 0; rr < 8; rr++) w0[rr] = *(const float2*)&wp[(size_t)(db + 16 + rr) * CHN];
        }
        #pragma unroll
        for (int i = 0; i < GRP; i++) {
            float4 ga = *(const float4*)&g[i][db + 8];
            float4 gb = *(const float4*)&g[i][db + 12];
            acc[i].x += ga.x*w1[0].x + ga.y*w1[1].x + ga.z*w1[2].x + ga.w*w1[3].x
                      + gb.x*w1[4].x + gb.y*w1[5].x + gb.z*w1[6].x + gb.w*w1[7].x;
            acc[i].y += ga.x*w1[0].y + ga.y*w1[1].y + ga.z*w1[2].y + ga.w*w1[3].y
                      + gb.x*w1[4].y + gb.y*w1[5].y + gb.z*w1[6].y + gb.w*w1[7].y;
        }
    }

    float2 bv = *(const float2*)&bh[h0];
    float wo0[4], wo1[4];
    #pragma unroll
    for (int o = 0; o < 4; o++) {
        wo0[o] = (o < no) ? Wo[h0 * no + o] : 0.f;
        wo1[o] = (o < no) ? Wo[(h0 + 1) * no + o] : 0.f;
    }

    for (int i = 0; i < n; i++) {
        float h0v = gelu_exact(acc[i].x + bv.x);
        float h1v = gelu_exact(acc[i].y + bv.y);
        #pragma unroll
        for (int o = 0; o < 4; o++) {
            if (o < no) {
                float p = h0v * wo0[o] + h1v * wo1[o];
                #pragma unroll
                for (int off = 32; off >= 1; off >>= 1) p += __shfl_down(p, off);
                if (lane == 0) atomicAdd(&pose[bl[i] * 7 + ob + o], p);
            }
        }
    }
}

extern "C" void kernel_launch(void* const* d_in, const int* in_sizes, int n_in,
                              void* d_out, int out_size, void* d_ws, size_t ws_size,
                              hipStream_t stream) {
    const float* dt    = (const float*)d_in[0];
    const float* dr    = (const float*)d_in[1];
    const float* Wsc   = (const float*)d_in[2];
    const float* bsc   = (const float*)d_in[3];
    const float* Wt_h  = (const float*)d_in[4];
    const float* bt_h  = (const float*)d_in[5];
    const float* Wt_o  = (const float*)d_in[6];
    const float* bt_o  = (const float*)d_in[7];
    const float* Wr_h  = (const float*)d_in[8];
    const float* br_h  = (const float*)d_in[9];
    const float* Wr_o  = (const float*)d_in[10];
    const float* br_o  = (const float*)d_in[11];

    float* pose = (float*)d_out;                    // [B,7]
    float* logd = (float*)d_out + BN * 7;           // [B,S]

    int* max_idx = (int*)d_ws;                              // 4 KB
    int* counts  = (int*)((char*)d_ws + 4096);              // 256 B
    int* lists   = (int*)((char*)d_ws + 8192);              // 256 KB

    hipMemsetAsync(counts, 0, SN * sizeof(int), stream);

    k_scene<<<BN, 256, 0, stream>>>(dt, dr, Wsc, bsc, logd, max_idx);
    k_prep<<<(BN * 7 + 255) / 256, 256, 0, stream>>>(max_idx, bt_o, br_o, pose, counts, lists);
    k_expert<<<1024, 128, 0, stream>>>(
        dt, dr, Wt_h, bt_h, Wt_o, Wr_h, br_h, Wr_o, counts, lists, pose);
}

// Round 4
// 373.802 us; speedup vs baseline: 1.0077x; 1.0077x over previous
//
#include <hip/hip_runtime.h>
#include <math.h>

#define BN 1024
#define SN 64
#define DN 256
#define CHN 1024
#define GRP 16

__device__ __forceinline__ float gelu_exact(float x) {
    return 0.5f * x * (1.0f + erff(x * 0.70710678118654752440f));
}

// K1: scene logits + log_softmax + argmax. One block per sample b, 256 thr = 4 waves.
__global__ __launch_bounds__(256, 4) void k_scene(
    const float* __restrict__ dt, const float* __restrict__ dr,
    const float* __restrict__ Wsc, const float* __restrict__ bsc,
    float* __restrict__ out_logd, int* __restrict__ max_idx)
{
    int b = blockIdx.x;
    int tid = threadIdx.x;
    int lane = tid & 63;
    int wave = tid >> 6;
    __shared__ float part[SN][65];   // +1 pad: reduction read is 2-way (free)
    __shared__ float logits[SN];

    float4 wt = *(const float4*)&Wsc[4 * lane];
    float4 wr = *(const float4*)&Wsc[DN + 4 * lane];
    const float* pt = dt + (size_t)b * SN * DN + 4 * lane;
    const float* pr = dr + (size_t)b * SN * DN + 4 * lane;
    float bias0 = bsc[0];

    float p[16];
    #pragma unroll 8
    for (int k = 0; k < 16; k++) {
        int s = wave * 16 + k;          // each wave streams a contiguous 16KB chunk
        float4 t4 = *(const float4*)&pt[s * DN];
        float4 r4 = *(const float4*)&pr[s * DN];
        p[k] = t4.x * wt.x + t4.y * wt.y + t4.z * wt.z + t4.w * wt.w
             + r4.x * wr.x + r4.y * wr.y + r4.z * wr.z + r4.w * wr.w;
    }
    #pragma unroll
    for (int k = 0; k < 16; k++) part[wave * 16 + k][lane] = p[k];
    __syncthreads();

    {
        int s = tid >> 2, q = tid & 3;
        float sum = 0.f;
        #pragma unroll
        for (int j = 0; j < 16; j++) sum += part[s][q * 16 + j];
        sum += __shfl_xor(sum, 1);
        sum += __shfl_xor(sum, 2);
        if (q == 0) logits[s] = sum + bias0;
    }
    __syncthreads();

    if (wave == 0) {
        float l = logits[lane];
        float m = l; int idx = lane;
        #pragma unroll
        for (int off = 32; off >= 1; off >>= 1) {
            float om = __shfl_xor(m, off);
            int oidx = __shfl_xor(idx, off);
            if (om > m || (om == m && oidx < idx)) { m = om; idx = oidx; }
        }
        float e = expf(l - m);
        float ssum = e;
        #pragma unroll
        for (int off = 32; off >= 1; off >>= 1) ssum += __shfl_xor(ssum, off);
        float logZ = m + logf(ssum);
        out_logd[b * SN + lane] = l - logZ;
        if (lane == 0) max_idx[b] = idx;
    }
}

// K2: fused pose-bias init + scene binning.
__global__ __launch_bounds__(256) void k_prep(
    const int* __restrict__ max_idx,
    const float* __restrict__ bt_o, const float* __restrict__ br_o,
    float* __restrict__ pose, int* __restrict__ counts, int* __restrict__ lists)
{
    int t = blockIdx.x * blockDim.x + threadIdx.x;
    if (t < BN * 7) {
        int b = t / 7, o = t % 7;
        int s = max_idx[b];
        pose[t] = (o < 3) ? bt_o[s * 3 + o] : br_o[s * 4 + (o - 3)];
    }
    if (t < BN) {
        int s = max_idx[t];
        int pos = atomicAdd(&counts[s], 1);
        lists[s * BN + pos] = t;
    }
}

// K3: expert MLP heads. Item = (scene, type, 256-col CH chunk, 16-sample group);
// equal 256KB weight streams -> balanced. ONE hidden unit per thread so the
// whole working set (acc[16] + w[8]) fits in ~56 VGPRs -> no scratch spill.
__global__ __launch_bounds__(256, 4) void k_expert(
    const float* __restrict__ dt, const float* __restrict__ dr,
    const float* __restrict__ Wt_h, const float* __restrict__ bt_h, const float* __restrict__ Wt_o,
    const float* __restrict__ Wr_h, const float* __restrict__ br_h, const float* __restrict__ Wr_o,
    const int* __restrict__ counts, const int* __restrict__ lists,
    float* __restrict__ pose)
{
    __shared__ float g[GRP][DN];     // 16 KB gathered descriptors
    __shared__ int pref[SN + 1];
    __shared__ int bl[GRP];
    int tid = threadIdx.x;
    int lane = tid & 63;
    int wave = tid >> 6;

    // group-count prefix scan (wave 0)
    if (wave == 0) {
        int c = counts[lane];
        int ng = (c + 15) >> 4;
        #pragma unroll
        for (int off = 1; off < 64; off <<= 1) {
            int v = __shfl_up(ng, off);
            if (lane >= off) ng += v;
        }
        pref[lane + 1] = ng;
        if (lane == 0) pref[0] = 0;
    }
    __syncthreads();

    int q = blockIdx.x;
    if (q >= pref[SN] * 8) return;   // uniform exit

    int s = 0;
    while (pref[s + 1] * 8 <= q) s++;
    int r = q - pref[s] * 8;
    int grp = r >> 3;
    int z = (r >> 2) & 1;
    int c4 = r & 3;

    int cnt = counts[s];
    int base = grp * GRP;
    int n = min(GRP, cnt - base);

    const float* Wh; const float* bh; const float* Wo; const float* descs; int no, ob;
    if (z == 0) {
        Wh = Wt_h + (size_t)s * DN * CHN; bh = bt_h + s * CHN;
        Wo = Wt_o + (size_t)s * CHN * 3;  descs = dt; no = 3; ob = 0;
    } else {
        Wh = Wr_h + (size_t)s * DN * CHN; bh = br_h + s * CHN;
        Wo = Wr_o + (size_t)s * CHN * 4;  descs = dr; no = 4; ob = 3;
    }

    for (int i = 0; i < GRP; i++) {
        int bi = 0; float v = 0.f;
        if (i < n) {
            bi = lists[s * BN + base + i];
            v = descs[(size_t)bi * SN * DN + s * DN + tid];
        }
        g[i][tid] = v;
        if (tid == 0) bl[i] = bi;
    }
    __syncthreads();

    int h0 = c4 * 256 + tid;         // ONE hidden unit per thread
    const float* wp = Wh + h0;
    float acc[GRP];
    #pragma unroll
    for (int i = 0; i < GRP; i++) acc[i] = 0.f;

    for (int db = 0; db < DN; db += 8) {
        float w[8];
        #pragma unroll
        for (int rr = 0; rr < 8; rr++) w[rr] = wp[(size_t)(db + rr) * CHN];
        #pragma unroll
        for (int i = 0; i < GRP; i++) {
            float4 ga = *(const float4*)&g[i][db];      // broadcast ds_read_b128
            float4 gb = *(const float4*)&g[i][db + 4];
            acc[i] += ga.x * w[0] + ga.y * w[1] + ga.z * w[2] + ga.w * w[3]
                    + gb.x * w[4] + gb.y * w[5] + gb.z * w[6] + gb.w * w[7];
        }
    }

    float hb = bh[h0];
    float wo[4];
    #pragma unroll
    for (int o = 0; o < 4; o++) wo[o] = (o < no) ? Wo[h0 * no + o] : 0.f;

    for (int i = 0; i < n; i++) {
        float hv = gelu_exact(acc[i] + hb);
        #pragma unroll
        for (int o = 0; o < 4; o++) {
            if (o < no) {
                float p = hv * wo[o];
                #pragma unroll
                for (int off = 32; off >= 1; off >>= 1) p += __shfl_down(p, off);
                if (lane == 0) atomicAdd(&pose[bl[i] * 7 + ob + o], p);
            }
        }
    }
}

extern "C" void kernel_launch(void* const* d_in, const int* in_sizes, int n_in,
                              void* d_out, int out_size, void* d_ws, size_t ws_size,
                              hipStream_t stream) {
    const float* dt    = (const float*)d_in[0];
    const float* dr    = (const float*)d_in[1];
    const float* Wsc   = (const float*)d_in[2];
    const float* bsc   = (const float*)d_in[3];
    const float* Wt_h  = (const float*)d_in[4];
    const float* bt_h  = (const float*)d_in[5];
    const float* Wt_o  = (const float*)d_in[6];
    const float* bt_o  = (const float*)d_in[7];
    const float* Wr_h  = (const float*)d_in[8];
    const float* br_h  = (const float*)d_in[9];
    const float* Wr_o  = (const float*)d_in[10];
    const float* br_o  = (const float*)d_in[11];

    float* pose = (float*)d_out;                    // [B,7]
    float* logd = (float*)d_out + BN * 7;           // [B,S]

    int* max_idx = (int*)d_ws;                              // 4 KB
    int* counts  = (int*)((char*)d_ws + 4096);              // 256 B
    int* lists   = (int*)((char*)d_ws + 8192);              // 256 KB

    hipMemsetAsync(counts, 0, SN * sizeof(int), stream);

    k_scene<<<BN, 256, 0, stream>>>(dt, dr, Wsc, bsc, logd, max_idx);
    k_prep<<<(BN * 7 + 255) / 256, 256, 0, stream>>>(max_idx, bt_o, br_o, pose, counts, lists);
    k_expert<<<1024, 256, 0, stream>>>(
        dt, dr, Wt_h, bt_h, Wt_o, Wr_h, br_h, Wr_o, counts, lists, pose);
}

// Round 5
// 299.621 us; speedup vs baseline: 1.2572x; 1.2476x over previous
//
#include <hip/hip_runtime.h>
#include <math.h>

#define BN 1024
#define SN 64
#define DN 256
#define CHN 1024
#define GRP 16

__device__ __forceinline__ float gelu_exact(float x) {
    return 0.5f * x * (1.0f + erff(x * 0.70710678118654752440f));
}

// K1: scene logits + log_softmax + argmax + pose-bias init + scene binning.
// One block per sample b, 256 thr = 4 waves.
__global__ __launch_bounds__(256, 4) void k_scene(
    const float* __restrict__ dt, const float* __restrict__ dr,
    const float* __restrict__ Wsc, const float* __restrict__ bsc,
    const float* __restrict__ bt_o, const float* __restrict__ br_o,
    float* __restrict__ out_logd, float* __restrict__ pose,
    int* __restrict__ counts, int* __restrict__ lists)
{
    int b = blockIdx.x;
    int tid = threadIdx.x;
    int lane = tid & 63;
    int wave = tid >> 6;
    __shared__ float part[SN][65];   // +1 pad: reduction read is 2-way (free)
    __shared__ float logits[SN];

    float4 wt = *(const float4*)&Wsc[4 * lane];
    float4 wr = *(const float4*)&Wsc[DN + 4 * lane];
    const float* pt = dt + (size_t)b * SN * DN + 4 * lane;
    const float* pr = dr + (size_t)b * SN * DN + 4 * lane;
    float bias0 = bsc[0];

    float p[16];
    #pragma unroll 8
    for (int k = 0; k < 16; k++) {
        int s = wave * 16 + k;          // each wave streams a contiguous 16KB chunk
        float4 t4 = *(const float4*)&pt[s * DN];
        float4 r4 = *(const float4*)&pr[s * DN];
        p[k] = t4.x * wt.x + t4.y * wt.y + t4.z * wt.z + t4.w * wt.w
             + r4.x * wr.x + r4.y * wr.y + r4.z * wr.z + r4.w * wr.w;
    }
    #pragma unroll
    for (int k = 0; k < 16; k++) part[wave * 16 + k][lane] = p[k];
    __syncthreads();

    {
        int s = tid >> 2, q = tid & 3;
        float sum = 0.f;
        #pragma unroll
        for (int j = 0; j < 16; j++) sum += part[s][q * 16 + j];
        sum += __shfl_xor(sum, 1);
        sum += __shfl_xor(sum, 2);
        if (q == 0) logits[s] = sum + bias0;
    }
    __syncthreads();

    if (wave == 0) {
        float l = logits[lane];
        float m = l; int idx = lane;
        #pragma unroll
        for (int off = 32; off >= 1; off >>= 1) {
            float om = __shfl_xor(m, off);
            int oidx = __shfl_xor(idx, off);
            if (om > m || (om == m && oidx < idx)) { m = om; idx = oidx; }
        }
        float e = expf(l - m);
        float ssum = e;
        #pragma unroll
        for (int off = 32; off >= 1; off >>= 1) ssum += __shfl_xor(ssum, off);
        float logZ = m + logf(ssum);
        out_logd[b * SN + lane] = l - logZ;
        // fused prep: bin this sample + write pose output biases
        if (lane == 0) {
            int pos = atomicAdd(&counts[idx], 1);
            lists[idx * BN + pos] = b;
        }
        if (lane < 7)
            pose[b * 7 + lane] = (lane < 3) ? bt_o[idx * 3 + lane]
                                            : br_o[idx * 4 + (lane - 3)];
    }
}

// K2: expert MLP heads. Item = (scene, type, 256-col CH chunk, 16-sample group);
// equal 256KB weight streams -> balanced. One hidden unit per thread.
// ALL acc[] accesses are constant-indexed (epilogue unrolled + predicated) so
// the accumulator array lives in VGPRs, not scratch.
__global__ __launch_bounds__(256, 4) void k_expert(
    const float* __restrict__ dt, const float* __restrict__ dr,
    const float* __restrict__ Wt_h, const float* __restrict__ bt_h, const float* __restrict__ Wt_o,
    const float* __restrict__ Wr_h, const float* __restrict__ br_h, const float* __restrict__ Wr_o,
    const int* __restrict__ counts, const int* __restrict__ lists,
    float* __restrict__ pose)
{
    __shared__ float g[GRP][DN];     // 16 KB gathered descriptors
    __shared__ int pref[SN + 1];
    __shared__ int bl[GRP];
    int tid = threadIdx.x;
    int lane = tid & 63;
    int wave = tid >> 6;

    // group-count prefix scan (wave 0)
    if (wave == 0) {
        int c = counts[lane];
        int ng = (c + 15) >> 4;
        #pragma unroll
        for (int off = 1; off < 64; off <<= 1) {
            int v = __shfl_up(ng, off);
            if (lane >= off) ng += v;
        }
        pref[lane + 1] = ng;
        if (lane == 0) pref[0] = 0;
    }
    __syncthreads();

    int q = blockIdx.x;
    if (q >= pref[SN] * 8) return;   // uniform exit

    int s = 0;
    while (pref[s + 1] * 8 <= q) s++;
    int r = q - pref[s] * 8;
    int grp = r >> 3;
    int z = (r >> 2) & 1;
    int c4 = r & 3;

    int cnt = counts[s];
    int base = grp * GRP;
    int n = min(GRP, cnt - base);

    const float* Wh; const float* bh; const float* Wo; const float* descs; int no, ob;
    if (z == 0) {
        Wh = Wt_h + (size_t)s * DN * CHN; bh = bt_h + s * CHN;
        Wo = Wt_o + (size_t)s * CHN * 3;  descs = dt; no = 3; ob = 0;
    } else {
        Wh = Wr_h + (size_t)s * DN * CHN; bh = br_h + s * CHN;
        Wo = Wr_o + (size_t)s * CHN * 4;  descs = dr; no = 4; ob = 3;
    }

    #pragma unroll 4
    for (int i = 0; i < GRP; i++) {
        int bi = 0; float v = 0.f;
        if (i < n) {
            bi = lists[s * BN + base + i];
            v = descs[(size_t)bi * SN * DN + s * DN + tid];
        }
        g[i][tid] = v;
        if (tid == 0) bl[i] = bi;
    }
    __syncthreads();

    int h0 = c4 * 256 + tid;         // one hidden unit per thread
    const float* wp = Wh + h0;
    float acc[GRP];
    #pragma unroll
    for (int i = 0; i < GRP; i++) acc[i] = 0.f;

    for (int db = 0; db < DN; db += 8) {
        float w[8];
        #pragma unroll
        for (int rr = 0; rr < 8; rr++) w[rr] = wp[(size_t)(db + rr) * CHN];
        #pragma unroll
        for (int i = 0; i < GRP; i++) {
            float4 ga = *(const float4*)&g[i][db];      // broadcast ds_read_b128
            float4 gb = *(const float4*)&g[i][db + 4];
            acc[i] += ga.x * w[0] + ga.y * w[1] + ga.z * w[2] + ga.w * w[3]
                    + gb.x * w[4] + gb.y * w[5] + gb.z * w[6] + gb.w * w[7];
        }
    }

    float hb = bh[h0];
    float wo[4];
    #pragma unroll
    for (int o = 0; o < 4; o++) wo[o] = (o < no) ? Wo[h0 * no + o] : 0.f;

    // epilogue: compile-time trip count + predication -> acc stays in VGPRs
    #pragma unroll
    for (int i = 0; i < GRP; i++) {
        if (i < n) {
            float hv = gelu_exact(acc[i] + hb);
            #pragma unroll
            for (int o = 0; o < 4; o++) {
                if (o < no) {
                    float p = hv * wo[o];
                    #pragma unroll
                    for (int off = 32; off >= 1; off >>= 1) p += __shfl_down(p, off);
                    if (lane == 0) atomicAdd(&pose[bl[i] * 7 + ob + o], p);
                }
            }
        }
    }
}

extern "C" void kernel_launch(void* const* d_in, const int* in_sizes, int n_in,
                              void* d_out, int out_size, void* d_ws, size_t ws_size,
                              hipStream_t stream) {
    const float* dt    = (const float*)d_in[0];
    const float* dr    = (const float*)d_in[1];
    const float* Wsc   = (const float*)d_in[2];
    const float* bsc   = (const float*)d_in[3];
    const float* Wt_h  = (const float*)d_in[4];
    const float* bt_h  = (const float*)d_in[5];
    const float* Wt_o  = (const float*)d_in[6];
    const float* bt_o  = (const float*)d_in[7];
    const float* Wr_h  = (const float*)d_in[8];
    const float* br_h  = (const float*)d_in[9];
    const float* Wr_o  = (const float*)d_in[10];
    const float* br_o  = (const float*)d_in[11];

    float* pose = (float*)d_out;                    // [B,7]
    float* logd = (float*)d_out + BN * 7;           // [B,S]

    int* counts  = (int*)((char*)d_ws + 4096);              // 256 B
    int* lists   = (int*)((char*)d_ws + 8192);              // 256 KB

    hipMemsetAsync(counts, 0, SN * sizeof(int), stream);

    k_scene<<<BN, 256, 0, stream>>>(dt, dr, Wsc, bsc, bt_o, br_o,
                                    logd, pose, counts, lists);
    k_expert<<<1024, 256, 0, stream>>>(
        dt, dr, Wt_h, bt_h, Wt_o, Wr_h, br_h, Wr_o, counts, lists, pose);
}